// Round 3
// baseline (533.016 us; speedup 1.0000x reference)
//
#include <hip/hip_runtime.h>

#define NCLS 100
#define EPS 1e-7f

// d_ws layout: counts[0..99]=pred_count, [100..199]=true_count, [200..299]=tp
__global__ void zero_counts_kernel(unsigned int* __restrict__ counts) {
    int i = threadIdx.x;
    if (i < 3 * NCLS) counts[i] = 0u;
}

__global__ __launch_bounds__(256) void hist_kernel(
        const float* __restrict__ logits,
        const int* __restrict__ labels,
        unsigned int* __restrict__ counts,
        int N) {
    __shared__ unsigned int s_pred[NCLS];
    __shared__ unsigned int s_true[NCLS];
    __shared__ unsigned int s_tp[NCLS];
    for (int i = threadIdx.x; i < NCLS; i += blockDim.x) {
        s_pred[i] = 0u; s_true[i] = 0u; s_tp[i] = 0u;
    }
    __syncthreads();

    const int tid    = blockIdx.x * blockDim.x + threadIdx.x;
    const int q      = tid & 3;        // lane within quad
    const int quad   = tid >> 2;       // global quad id = row id
    const int nquads = (gridDim.x * blockDim.x) >> 2;

    const float4* f4base = (const float4*)logits;

    for (int row = quad; row < N; row += nquads) {
        // Row r occupies float4s [25r, 25r+25), spanning exactly 7 cache
        // lines starting at the 64B-aligned float4 index A = (25r) & ~3.
        // Lane q loads A + 4k + q (k=0..6): every request is a fully-dense,
        // line-aligned 64B chunk -> zero straddle, no request amplification.
        const size_t rowf4 = (size_t)row * 25;
        const size_t A     = rowf4 & ~(size_t)3;
        const int    r3    = row & 3;          // = 25r mod 4

        float4 v[7];
        #pragma unroll
        for (int k = 0; k < 7; ++k) v[k] = f4base[A + 4 * k + q];

        // Column of element e of v[k]: col = 16k + 4(q - r3) + e.
        // Out-of-row slots (col<0 or col>=100) are masked out.
        const int off = (q - r3) << 2;

        float best = -INFINITY;
        int bidx = 0;
        #pragma unroll
        for (int k = 0; k < 7; ++k) {
            const int cb = 16 * k + off;
            float4 w = v[k];
            if ((unsigned)(cb + 0) < (unsigned)NCLS && w.x > best) { best = w.x; bidx = cb;     }
            if ((unsigned)(cb + 1) < (unsigned)NCLS && w.y > best) { best = w.y; bidx = cb + 1; }
            if ((unsigned)(cb + 2) < (unsigned)NCLS && w.z > best) { best = w.z; bidx = cb + 2; }
            if ((unsigned)(cb + 3) < (unsigned)NCLS && w.w > best) { best = w.w; bidx = cb + 3; }
        }

        // Quad-wide argmax: greater value wins; tie -> lower column index
        // (preserves jnp.argmax first-max semantics; per-lane cols ascend).
        #pragma unroll
        for (int m = 1; m <= 2; m <<= 1) {
            float ob = __shfl_xor(best, m, 64);
            int   oi = __shfl_xor(bidx, m, 64);
            if (ob > best || (ob == best && oi < bidx)) { best = ob; bidx = oi; }
        }

        if (q == 0) {
            int lab = labels[row];
            atomicAdd(&s_pred[bidx], 1u);
            atomicAdd(&s_true[lab], 1u);
            if (bidx == lab) atomicAdd(&s_tp[lab], 1u);
        }
    }

    __syncthreads();
    for (int i = threadIdx.x; i < NCLS; i += blockDim.x) {
        unsigned int v;
        if ((v = s_pred[i]) != 0u) atomicAdd(&counts[i], v);
        if ((v = s_true[i]) != 0u) atomicAdd(&counts[NCLS + i], v);
        if ((v = s_tp[i])   != 0u) atomicAdd(&counts[2 * NCLS + i], v);
    }
}

__global__ void finalize_kernel(const unsigned int* __restrict__ counts,
                                float* __restrict__ out) {
    __shared__ float s_f1[NCLS];
    int c = threadIdx.x;
    if (c < NCLS) {
        float tp    = (float)counts[2 * NCLS + c];
        float predc = (float)counts[c];            // tp + fp
        float truec = (float)counts[NCLS + c];     // tp + fn
        float fp = predc - tp;
        float fn = truec - tp;
        float precision = tp / (tp + fp + EPS);
        float recall    = tp / (tp + fn + EPS);
        float f1 = 2.0f * precision * recall / (precision + recall + EPS);
        s_f1[c] = f1;
    }
    __syncthreads();
    if (c == 0) {
        float sum = 0.0f;
        for (int i = 0; i < NCLS; ++i) sum += s_f1[i];
        out[0] = sum / (float)NCLS;
    }
}

extern "C" void kernel_launch(void* const* d_in, const int* in_sizes, int n_in,
                              void* d_out, int out_size, void* d_ws, size_t ws_size,
                              hipStream_t stream) {
    const float* logits = (const float*)d_in[0];
    const int*   labels = (const int*)d_in[1];
    float* out = (float*)d_out;
    unsigned int* counts = (unsigned int*)d_ws;  // 300 u32 = 1200 B scratch

    const int N = in_sizes[1];  // 1,000,000 rows

    zero_counts_kernel<<<1, 320, 0, stream>>>(counts);

    const int block = 256;
    const int grid  = 2048;  // 8 blocks/CU, grid-stride over row quads
    hist_kernel<<<grid, block, 0, stream>>>(logits, labels, counts, N);

    finalize_kernel<<<1, 128, 0, stream>>>(counts, out);
}

// Round 4
// 526.825 us; speedup vs baseline: 1.0118x; 1.0118x over previous
//
#include <hip/hip_runtime.h>

#define NCLS 100
#define EPS 1e-7f
#define ROWS_PER_BLOCK 512   // must be multiple of 64
#define N_ITER (ROWS_PER_BLOCK / 64)

// d_ws layout: counts[0..99]=pred_count, [100..199]=true_count, [200..299]=tp
__global__ void zero_counts_kernel(unsigned int* __restrict__ counts) {
    int i = threadIdx.x;
    if (i < 3 * NCLS) counts[i] = 0u;
}

__device__ __forceinline__ void load7(const float4* __restrict__ f4,
                                      int r, int q, int rowEnd,
                                      float4 v[7], int* lab,
                                      const int* __restrict__ labels) {
    if (r < rowEnd) {
        const size_t A = ((size_t)r * 25) & ~(size_t)3;
        #pragma unroll
        for (int k = 0; k < 7; ++k) v[k] = f4[A + 4 * k + q];
        if (q == 0) *lab = labels[r];
    }
}

__device__ __forceinline__ void process7(const float4 v[7], int r, int q,
                                         int rowEnd, int lab,
                                         unsigned int* s_pred,
                                         unsigned int* s_true,
                                         unsigned int* s_tp) {
    float best = -INFINITY;
    int bidx = 0;
    if (r < rowEnd) {
        const int r3 = r & 3;                 // = 25r mod 4
        const int off = (q - r3) << 2;
        #pragma unroll
        for (int k = 0; k < 7; ++k) {
            const int cb = 16 * k + off;      // col of element 0 of v[k]
            float4 w = v[k];
            if ((unsigned)(cb + 0) < (unsigned)NCLS && w.x > best) { best = w.x; bidx = cb;     }
            if ((unsigned)(cb + 1) < (unsigned)NCLS && w.y > best) { best = w.y; bidx = cb + 1; }
            if ((unsigned)(cb + 2) < (unsigned)NCLS && w.z > best) { best = w.z; bidx = cb + 2; }
            if ((unsigned)(cb + 3) < (unsigned)NCLS && w.w > best) { best = w.w; bidx = cb + 3; }
        }
    }
    // Quad-wide argmax (validity is quad-uniform): greater wins; tie -> lower col.
    #pragma unroll
    for (int m = 1; m <= 2; m <<= 1) {
        float ob = __shfl_xor(best, m, 64);
        int   oi = __shfl_xor(bidx, m, 64);
        if (ob > best || (ob == best && oi < bidx)) { best = ob; bidx = oi; }
    }
    if (q == 0 && r < rowEnd) {
        atomicAdd(&s_pred[bidx], 1u);
        atomicAdd(&s_true[lab], 1u);
        if (bidx == lab) atomicAdd(&s_tp[lab], 1u);
    }
}

__global__ __launch_bounds__(256) void hist_kernel(
        const float* __restrict__ logits,
        const int* __restrict__ labels,
        unsigned int* __restrict__ counts,
        int N) {
    __shared__ unsigned int s_pred[NCLS];
    __shared__ unsigned int s_true[NCLS];
    __shared__ unsigned int s_tp[NCLS];
    for (int i = threadIdx.x; i < NCLS; i += blockDim.x) {
        s_pred[i] = 0u; s_true[i] = 0u; s_tp[i] = 0u;
    }
    __syncthreads();

    const int lane = threadIdx.x & 63;
    const int wv   = threadIdx.x >> 6;    // wave in block, 0..3
    const int q    = lane & 3;            // lane in quad
    const int g    = lane >> 2;           // quad in wave, 0..15

    const int blockStart = blockIdx.x * ROWS_PER_BLOCK;
    const int rowEnd     = min(blockStart + ROWS_PER_BLOCK, N);

    const float4* f4 = (const float4*)logits;

    // Wave w handles rows blockStart + w*16 + g + 64*i  (block advances by a
    // dense 64-row / 25.6KB window per iteration; blocks own contiguous chunks).
    int row = blockStart + wv * 16 + g;

    float4 va[7], vb[7];
    int la = 0, lb = 0;

    load7(f4, row, q, rowEnd, va, &la, labels);

    // 2-deep pipeline, manually unrolled x2 to avoid register copies.
    #pragma unroll 1
    for (int i = 0; i < N_ITER; i += 2) {
        const int r1 = row + 64;
        load7(f4, r1, q, rowEnd, vb, &lb, labels);        // in flight during...
        process7(va, row, q, rowEnd, la, s_pred, s_true, s_tp);

        const int r2 = r1 + 64;
        if (i + 2 < N_ITER) {
            load7(f4, r2, q, rowEnd, va, &la, labels);    // in flight during...
        }
        process7(vb, r1, q, rowEnd, lb, s_pred, s_true, s_tp);

        row = r2;
    }

    __syncthreads();
    for (int i = threadIdx.x; i < NCLS; i += blockDim.x) {
        unsigned int v;
        if ((v = s_pred[i]) != 0u) atomicAdd(&counts[i], v);
        if ((v = s_true[i]) != 0u) atomicAdd(&counts[NCLS + i], v);
        if ((v = s_tp[i])   != 0u) atomicAdd(&counts[2 * NCLS + i], v);
    }
}

__global__ void finalize_kernel(const unsigned int* __restrict__ counts,
                                float* __restrict__ out) {
    __shared__ float s_f1[NCLS];
    int c = threadIdx.x;
    if (c < NCLS) {
        float tp    = (float)counts[2 * NCLS + c];
        float predc = (float)counts[c];            // tp + fp
        float truec = (float)counts[NCLS + c];     // tp + fn
        float fp = predc - tp;
        float fn = truec - tp;
        float precision = tp / (tp + fp + EPS);
        float recall    = tp / (tp + fn + EPS);
        float f1 = 2.0f * precision * recall / (precision + recall + EPS);
        s_f1[c] = f1;
    }
    __syncthreads();
    if (c == 0) {
        float sum = 0.0f;
        for (int i = 0; i < NCLS; ++i) sum += s_f1[i];
        out[0] = sum / (float)NCLS;
    }
}

extern "C" void kernel_launch(void* const* d_in, const int* in_sizes, int n_in,
                              void* d_out, int out_size, void* d_ws, size_t ws_size,
                              hipStream_t stream) {
    const float* logits = (const float*)d_in[0];
    const int*   labels = (const int*)d_in[1];
    float* out = (float*)d_out;
    unsigned int* counts = (unsigned int*)d_ws;  // 300 u32 = 1200 B scratch

    const int N = in_sizes[1];  // 1,000,000 rows

    zero_counts_kernel<<<1, 320, 0, stream>>>(counts);

    const int block = 256;
    const int grid  = (N + ROWS_PER_BLOCK - 1) / ROWS_PER_BLOCK;  // 1954
    hist_kernel<<<grid, block, 0, stream>>>(logits, labels, counts, N);

    finalize_kernel<<<1, 128, 0, stream>>>(counts, out);
}